// Round 11
// baseline (25.439 us; speedup 1.0000x reference)
//
#include <hip/hip_runtime.h>

// TBSyntaxParser v11: single kernel, 768 threads (12 waves, 3/SIMD), K=16
// MFMA fragments so the ENTIRE W1 (bf16 pair-packed, transposed) fits
// block-shared LDS (SLABW=185 words/col, 148 KB). One flat staging job space,
// one barrier, B-fragments via ds_read2_b32 post-barrier.
// B=4096, L=128, D=60, X=360(k, 23 k-tiles of 16, pad to 368), HID=200, OUT=3.
// d_out = [out (B*3) | legal (B*3)] f32.

#define Bq    4096
#define Lq    128
#define Dq    60
#define HIDq  200
#define ONUM  3
#define NKT   23        // k-tiles of 16 (368; k in [360,368) zero)
#define MB    16        // states per block
#define NTHR  768       // 12 waves
#define SLABW 185       // words per n-column (184 k2 + 1; %32=25 bank spread)
#define NTASK 13        // n-tiles of 16 (208; cols >=200 invalid)

typedef short bf16x4 __attribute__((ext_vector_type(4)));
typedef short bf16x8 __attribute__((ext_vector_type(8)));
typedef float f32x4  __attribute__((ext_vector_type(4)));

__device__ __forceinline__ unsigned int rhu(float f) {
    union { float f; unsigned int u; } x; x.f = f;
    return x.u + 0x8000u;                      // round-half-up into bf16 slot
}
// pack two rounded floats -> (bf16(hi)<<16) | bf16(lo) in one v_perm_b32
__device__ __forceinline__ unsigned pack2(float lo, float hi) {
    return __builtin_amdgcn_perm(rhu(hi), rhu(lo), 0x07060302u);
}

__global__ __launch_bounds__(NTHR, 3) void parser_k16(
    const float* __restrict__ buffer,
    const float* __restrict__ W1,
    const float* __restrict__ b1,
    const float* __restrict__ W2,
    const float* __restrict__ b2,
    const int*   __restrict__ buffer_index,
    const int*   __restrict__ stack_indexes,
    const int*   __restrict__ stack_len,
    float*       __restrict__ out)
{
    __shared__ unsigned       wbuf[HIDq * SLABW];      // 148,000 B: W1^T bf16-pairs
    __shared__ unsigned short Afrag[NKT * 64 * 4];     // 11,776 B: A fragments
    __shared__ float          psum[NTASK][MB][ONUM];   // 2,496 B

    const int t  = threadIdx.x;
    const int w  = t >> 6;          // 0..11
    const int l  = t & 63;
    const int s0 = blockIdx.x * MB;

    // ---- P1: gather index loads (oldest in VMEM FIFO) ----
    int g_s[2], g_k0[2], g_row[2];
    bool g_ok[2];
    #pragma unroll
    for (int m = 0; m < 2; ++m) {
        int i = t + m * NTHR;
        g_ok[m] = (m == 0) || (t < 672);             // 1440 jobs
        if (g_ok[m]) {
            int s = i / 90, r = i % 90, seg = r / 15, f = r % 15;
            g_s[m]  = s;
            g_k0[m] = seg * 60 + f * 4;
            g_row[m] = (seg < 3) ? (buffer_index[s0 + s] + seg)
                                 : stack_indexes[(s0 + s) * 3 + (seg - 3)];
        } else { g_s[m] = 0; g_k0[m] = 0; g_row[m] = 0; }
    }

    // ---- P2: W1 staging loads, flat job space (50 col-groups x 184 k2) ----
    // job j: cg = j/184, k2 = j%184; loads W1[2k2][cg*4..+3] and W1[2k2+1][..]
    float4 sa[12], sb[12];
    #pragma unroll
    for (int r = 0; r < 12; ++r) {
        int j  = r * NTHR + t;
        int cg = j / 184, k2 = j - cg * 184;
        bool live = (j < 9200) && (k2 < 180);        // real k rows only
        if (live) {
            const float* p = W1 + (size_t)(2 * k2) * HIDq + cg * 4;
            sa[r] = *(const float4*)p;
            sb[r] = *(const float4*)(p + HIDq);
        } else {
            sa[r] = (float4){0.f, 0.f, 0.f, 0.f};
            sb[r] = (float4){0.f, 0.f, 0.f, 0.f};
        }
    }

    // ---- P3: gather buffer float4 loads (address dep on idx only) ----
    float4 gv[2];
    #pragma unroll
    for (int m = 0; m < 2; ++m) {
        if (g_ok[m]) {
            gv[m] = *(const float4*)(buffer +
                     ((size_t)(s0 + g_s[m]) * Lq + g_row[m]) * Dq + (g_k0[m] % 60));
        } else {
            gv[m] = (float4){0.f, 0.f, 0.f, 0.f};
        }
    }

    // ---- epilogue constants (tail of VMEM FIFO; needed post-barrier) ----
    const int n0 = w * 16 + (l & 15);                // <= 191, always valid
    float bb0 = b1[n0];
    float w2a0 = W2[n0 * ONUM + 0], w2a1 = W2[n0 * ONUM + 1], w2a2 = W2[n0 * ONUM + 2];
    float bbX = 0.f, w2x0 = 0.f, w2x1 = 0.f, w2x2 = 0.f;
    if (w == 0) {                                    // wave 0 also runs n-tile 12
        int c = 192 + (l & 15);
        if (c < HIDq) {
            bbX = b1[c];
            w2x0 = W2[c * ONUM + 0]; w2x1 = W2[c * ONUM + 1]; w2x2 = W2[c * ONUM + 2];
        }
    }

    // ---- P4: W1 pack + ds_write (waits W1 loads; gv stays in flight) ----
    #pragma unroll
    for (int r = 0; r < 12; ++r) {
        int j  = r * NTHR + t;
        int cg = j / 184, k2 = j - cg * 184;
        if (j < 9200) {
            int base = (cg * 4) * SLABW + k2;
            wbuf[base            ] = pack2(sa[r].x, sb[r].x);
            wbuf[base +     SLABW] = pack2(sa[r].y, sb[r].y);
            wbuf[base + 2 * SLABW] = pack2(sa[r].z, sb[r].z);
            wbuf[base + 3 * SLABW] = pack2(sa[r].w, sb[r].w);
        }
    }

    // ---- P5: gather pack + Afrag writes ----
    // X[s][k0..k0+3] -> Afrag[kt = k0>>4][lane = s + 16*((k0>>2)&3)][e=0..3]
    #pragma unroll
    for (int m = 0; m < 2; ++m) {
        if (g_ok[m]) {
            int kt    = g_k0[m] >> 4;
            int lslot = g_s[m] + (((g_k0[m] >> 2) & 3) << 4);
            uint2 pk;
            pk.x = pack2(gv[m].x, gv[m].y);
            pk.y = pack2(gv[m].z, gv[m].w);
            *((uint2*)&Afrag[(size_t)(kt * 64 + lslot) * 4]) = pk;
        }
    }
    // zero Afrag pad: kt=22, lanes 32..63 (k in [360,368))
    if (t < 32) {
        uint2 z = {0u, 0u};
        *((uint2*)&Afrag[(size_t)(22 * 64 + 32 + t) * 4]) = z;
    }
    // legal mask (independent of MLP)
    if (t < MB * ONUM) {
        int s = t / ONUM, o = t % ONUM;
        int bi = buffer_index[s0 + s];
        int sl = stack_len[s0 + s];
        float lg;
        if (o == 0)      lg = (bi + 3 >= Lq) ? 0.f : 1.f;
        else if (o == 1) lg = (sl <= 3)      ? 0.f : 1.f;
        else             lg = (sl <= 4)      ? 0.f : 1.f;
        out[(size_t)Bq * ONUM + (size_t)(s0 + s) * ONUM + o] = lg;
    }

    __syncthreads();

    // ---- MFMA phase: wave w -> n-tile w; wave 0 also n-tile 12 ----
    const int ntasks = (w == 0) ? 2 : 1;
    for (int q = 0; q < ntasks; ++q) {
        const int nt    = q ? 12 : w;
        const int col   = nt * 16 + (l & 15);
        const bool cok  = col < HIDq;
        const int bbase = col * SLABW + ((l >> 4) << 1);

        f32x4 acc = {};
        #pragma unroll
        for (int kt = 0; kt < NKT; ++kt) {
            bf16x4 a = *((const bf16x4*)&Afrag[(size_t)(kt * 64 + l) * 4]);
            unsigned bw0 = 0u, bw1 = 0u;
            if (cok) {
                bw0 = wbuf[bbase + kt * 8];
                bw1 = wbuf[bbase + kt * 8 + 1];
            }
            union { unsigned u[2]; bf16x4 v; } bb;
            bb.u[0] = bw0; bb.u[1] = bw1;
#if __has_builtin(__builtin_amdgcn_mfma_f32_16x16x16bf16_1k)
            acc = __builtin_amdgcn_mfma_f32_16x16x16bf16_1k(a, bb.v, acc, 0, 0, 0);
#else
            bf16x8 a8 = {a[0], a[1], a[2], a[3], 0, 0, 0, 0};
            bf16x8 b8 = {bb.v[0], bb.v[1], bb.v[2], bb.v[3], 0, 0, 0, 0};
            acc = __builtin_amdgcn_mfma_f32_16x16x32_bf16(a8, b8, acc, 0, 0, 0);
#endif
        }

        // fused epilogue: bias + ReLU + layer-2 partials
        const float bb  = q ? bbX  : bb0;
        const float c0  = q ? w2x0 : w2a0;
        const float c1  = q ? w2x1 : w2a1;
        const float c2  = q ? w2x2 : w2a2;
        float p0[4], p1[4], p2[4];
        #pragma unroll
        for (int r = 0; r < 4; ++r) {
            float h = acc[r] + bb; h = h > 0.f ? h : 0.f;   // consts 0 if col invalid
            p0[r] = h * c0; p1[r] = h * c1; p2[r] = h * c2;
        }
        // butterfly-reduce over the 16-lane j-group
        #pragma unroll
        for (int d = 1; d < 16; d <<= 1) {
            #pragma unroll
            for (int r = 0; r < 4; ++r) {
                p0[r] += __shfl_xor(p0[r], d, 64);
                p1[r] += __shfl_xor(p1[r], d, 64);
                p2[r] += __shfl_xor(p2[r], d, 64);
            }
        }
        if ((l & 15) == 0) {
            #pragma unroll
            for (int r = 0; r < 4; ++r) {
                int s = ((l >> 4) << 2) + r;
                psum[nt][s][0] = p0[r];
                psum[nt][s][1] = p1[r];
                psum[nt][s][2] = p2[r];
            }
        }
    }
    __syncthreads();

    // ---- combine 13 n-tile partials + bias ----
    if (t < MB * ONUM) {
        int s = t / ONUM, o = t % ONUM;
        float v = b2[o];
        #pragma unroll
        for (int q = 0; q < NTASK; ++q) v += psum[q][s][o];
        out[(size_t)(s0 + s) * ONUM + o] = v;
    }
}

extern "C" void kernel_launch(void* const* d_in, const int* in_sizes, int n_in,
                              void* d_out, int out_size, void* d_ws, size_t ws_size,
                              hipStream_t stream) {
    const float* buffer        = (const float*)d_in[0];
    const float* W1            = (const float*)d_in[1];
    const float* b1            = (const float*)d_in[2];
    const float* W2            = (const float*)d_in[3];
    const float* b2            = (const float*)d_in[4];
    const int*   buffer_index  = (const int*)d_in[5];
    const int*   stack_indexes = (const int*)d_in[6];
    const int*   stack_len     = (const int*)d_in[7];
    float*       out           = (float*)d_out;

    parser_k16<<<Bq / MB, NTHR, 0, stream>>>(
        buffer, W1, b1, W2, b2, buffer_index, stack_indexes, stack_len, out);
}

// Round 13
// 13.651 us; speedup vs baseline: 1.8636x; 1.8636x over previous
//
#include <hip/hip_runtime.h>

// TBSyntaxParser v12b: v10 structure + forced materialization of the W1
// register-staged load streams (component-wise asm keepalives AFTER the full
// stream has issued) so the 24-load pipeline stays deep instead of being
// sunk to ~4-deep by the compiler (R6 evidence: VGPR_Count=60).
// Gather float4s issue after the slab stream, so the slab keepalive's
// vmcnt wait leaves them in flight (in-order FIFO).
// B=4096, L=128, D=60, X=360(k, pad 384), HID=200(n), OUT=3.
// d_out = [out (B*3) | legal (B*3)] f32.

#define Bq    4096
#define Lq    128
#define Dq    60
#define HIDq  200
#define ONUM  3
#define KTN   12        // k-tiles (384/32)
#define MB    16        // states per block (MFMA M)
#define NTHR  512       // 8 waves
#define SLABW 196       // words per n-column (192 k-pairs + 4 pad)

typedef short bf16x8 __attribute__((ext_vector_type(8)));
typedef float f32x4  __attribute__((ext_vector_type(4)));

__device__ __forceinline__ unsigned int rhu(float f) {
    union { float f; unsigned int u; } x; x.f = f;
    return x.u + 0x8000u;                      // round-half-up into bf16 slot
}
// pack two rounded floats -> (bf16(hi)<<16) | bf16(lo) in one v_perm_b32
__device__ __forceinline__ unsigned pack2(float lo, float hi) {
    return __builtin_amdgcn_perm(rhu(hi), rhu(lo), 0x07060302u);
}

// keepalive for a float4 without struct asm constraints
__device__ __forceinline__ void keep4(const float4& v) {
    asm volatile("" :: "v"(v.x), "v"(v.y), "v"(v.z), "v"(v.w));
}

__global__ __launch_bounds__(NTHR, 1) void parser_fused(
    const float* __restrict__ buffer,
    const float* __restrict__ W1,
    const float* __restrict__ b1,
    const float* __restrict__ W2,
    const float* __restrict__ b2,
    const int*   __restrict__ buffer_index,
    const int*   __restrict__ stack_indexes,
    const int*   __restrict__ stack_len,
    float*       __restrict__ out)
{
    __shared__ unsigned short Afrag[KTN * 64 * 8];     // 12 KiB
    __shared__ unsigned int   wbuf[8][16 * SLABW];     // 100.4 KiB wave-private
    __shared__ float          psum[8][MB][ONUM];       // 1.5 KiB

    const int t  = threadIdx.x;
    const int w  = t >> 6;
    const int l  = t & 63;
    const int s0 = blockIdx.x * MB;
    const bool hasB1 = (w < 5);

    // ---- P1: gather index loads (oldest in VMEM FIFO) ----
    int g_s[3], g_k0[3], g_seg[3], g_ri[3];
    bool g_ok[3];
    #pragma unroll
    for (int m = 0; m < 3; ++m) {
        int i = t + m * 512;
        g_ok[m] = (m < 2) || (t < 416);              // 1440 jobs
        if (g_ok[m]) {
            int s = i / 90, r = i % 90, seg = r / 15, f = r % 15;
            g_s[m] = s; g_seg[m] = seg; g_k0[m] = seg * 60 + f * 4;
            g_ri[m] = (seg < 3) ? buffer_index[s0 + s]
                                : stack_indexes[(s0 + s) * 3 + (seg - 3)];
        } else { g_s[m] = 0; g_seg[m] = 0; g_k0[m] = 0; g_ri[m] = 0; }
    }

    // ---- P2: slab0 W1 loads, register-staged (24 loads, deep pipeline) ----
    float4 sa[12], sb[12];
    #pragma unroll
    for (int it = 0; it < 12; ++it) {
        int j = it * 64 + l;
        if (it < 11 || l < 16) {                     // j < 720
            int k2 = j >> 2, nq = j & 3;
            int nb = w * 16 + nq * 4;                // <= 124, no guard
            const float* p = W1 + (size_t)(2 * k2) * HIDq + nb;
            sa[it] = *(const float4*)p;
            sb[it] = *(const float4*)(p + HIDq);
        } else {
            sa[it] = (float4){0.f, 0.f, 0.f, 0.f};
            sb[it] = (float4){0.f, 0.f, 0.f, 0.f};
        }
    }

    // ---- P3: gather buffer float4 loads (newer in FIFO than slab0) ----
    float4 gv[3];
    #pragma unroll
    for (int m = 0; m < 3; ++m) {
        if (g_ok[m]) {
            int row = (g_seg[m] < 3) ? (g_ri[m] + g_seg[m]) : g_ri[m];
            int off = g_k0[m] % 60;
            gv[m] = *(const float4*)(buffer +
                     ((size_t)(s0 + g_s[m]) * Lq + row) * Dq + off);
        } else {
            gv[m] = (float4){0.f, 0.f, 0.f, 0.f};
        }
    }

    // ---- FORCE slab0 materialization: one drain of the 24-load stream. ----
    // gv loads are NEWER in the in-order VMEM FIFO, so they stay in flight.
    #pragma unroll
    for (int it = 0; it < 12; ++it) { keep4(sa[it]); keep4(sb[it]); }

    // zero wbuf k-pad words k2 in [180,192) for this wave's 16 columns
    #pragma unroll
    for (int z = 0; z < 3; ++z) {
        int idx = z * 64 + l;
        wbuf[w][(idx / 12) * SLABW + 180 + (idx % 12)] = 0u;
    }

    // ---- P4: pack slab0 + ds_write ----
    #pragma unroll
    for (int it = 0; it < 12; ++it) {
        int j = it * 64 + l;
        if (it < 11 || l < 16) {
            int k2 = j >> 2, nq = j & 3;
            wbuf[w][(nq * 4 + 0) * SLABW + k2] = pack2(sa[it].x, sb[it].x);
            wbuf[w][(nq * 4 + 1) * SLABW + k2] = pack2(sa[it].y, sb[it].y);
            wbuf[w][(nq * 4 + 2) * SLABW + k2] = pack2(sa[it].z, sb[it].z);
            wbuf[w][(nq * 4 + 3) * SLABW + k2] = pack2(sa[it].w, sb[it].w);
        }
    }

    // ---- P5: slab1 W1 loads, register-staged (sa/sb dead; regs reused) ----
    float4 ta[12], tb[12];
    if (hasB1) {
        #pragma unroll
        for (int it = 0; it < 12; ++it) {
            int j = it * 64 + l;
            if (it < 11 || l < 16) {
                int k2 = j >> 2, nq = j & 3;
                int nb = 128 + w * 16 + nq * 4;      // up to 204 for w==4
                if (nb < HIDq) {
                    const float* p = W1 + (size_t)(2 * k2) * HIDq + nb;
                    ta[it] = *(const float4*)p;
                    tb[it] = *(const float4*)(p + HIDq);
                } else {
                    ta[it] = (float4){0.f, 0.f, 0.f, 0.f};
                    tb[it] = (float4){0.f, 0.f, 0.f, 0.f};
                }
            }
        }
    }

    // ---- epilogue constants ----
    const int  n0   = w * 16 + (l & 15);
    const int  n1   = (8 + w) * 16 + (l & 15);
    const bool n1ok = n1 < HIDq;
    float bb0 = b1[n0];
    float w20 = W2[n0 * ONUM + 0], w21 = W2[n0 * ONUM + 1], w22 = W2[n0 * ONUM + 2];
    float bb1 = 0.f, w23 = 0.f, w24 = 0.f, w25 = 0.f;
    if (hasB1 && n1ok) {
        bb1 = b1[n1];
        w23 = W2[n1 * ONUM + 0]; w24 = W2[n1 * ONUM + 1]; w25 = W2[n1 * ONUM + 2];
    }

    // ---- P6: B0 fragment ds_reads (slab0 written; same-wave lgkm order) ----
    bf16x8 B0[KTN], B1[KTN];
    #pragma unroll
    for (int kt = 0; kt < KTN; ++kt)
        B0[kt] = *((const bf16x8*)&wbuf[w][(l & 15) * SLABW + kt * 16 + ((l >> 4) << 2)]);

    // ---- P7: gather pack + Afrag writes + legal mask ----
    #pragma unroll
    for (int m = 0; m < 3; ++m) {
        if (g_ok[m]) {
            int kt   = g_k0[m] >> 5;
            int lane = g_s[m] + (((g_k0[m] & 31) >> 3) << 4);
            uint2 pk;
            pk.x = pack2(gv[m].x, gv[m].y);
            pk.y = pack2(gv[m].z, gv[m].w);
            *((uint2*)&Afrag[(size_t)(kt * 64 + lane) * 8 + (g_k0[m] & 7)]) = pk;
        }
    }
    if (t < 48) {                                    // zero Afrag kt=11 pad
        f32x4 z = {0.f, 0.f, 0.f, 0.f};
        *((f32x4*)&Afrag[(size_t)(11 * 64 + 16 + t) * 8]) = z;
    }
    if (t < MB * ONUM) {                             // legal mask
        int s = t / ONUM, o = t % ONUM;
        int bi = buffer_index[s0 + s];
        int sl = stack_len[s0 + s];
        float lg;
        if (o == 0)      lg = (bi + 3 >= Lq) ? 0.f : 1.f;
        else if (o == 1) lg = (sl <= 3)      ? 0.f : 1.f;
        else             lg = (sl <= 4)      ? 0.f : 1.f;
        out[(size_t)Bq * ONUM + (size_t)(s0 + s) * ONUM + o] = lg;
    }

    // ---- FORCE slab1 materialization (stream fully issued back at P5) ----
    if (hasB1) {
        #pragma unroll
        for (int it = 0; it < 12; ++it) { keep4(ta[it]); keep4(tb[it]); }
    }

    // ---- P8: pack slab1 + ds_write, then B1 reads ----
    if (hasB1) {
        #pragma unroll
        for (int it = 0; it < 12; ++it) {
            int j = it * 64 + l;
            if (it < 11 || l < 16) {
                int k2 = j >> 2, nq = j & 3;
                wbuf[w][(nq * 4 + 0) * SLABW + k2] = pack2(ta[it].x, tb[it].x);
                wbuf[w][(nq * 4 + 1) * SLABW + k2] = pack2(ta[it].y, tb[it].y);
                wbuf[w][(nq * 4 + 2) * SLABW + k2] = pack2(ta[it].z, tb[it].z);
                wbuf[w][(nq * 4 + 3) * SLABW + k2] = pack2(ta[it].w, tb[it].w);
            }
        }
        #pragma unroll
        for (int kt = 0; kt < KTN; ++kt)
            B1[kt] = *((const bf16x8*)&wbuf[w][(l & 15) * SLABW + kt * 16 + ((l >> 4) << 2)]);
    }

    __syncthreads();

    // ---- layer 1 MFMA: A from LDS, B in registers ----
    f32x4 acc0 = {}, acc1 = {};
    #pragma unroll
    for (int kt = 0; kt < KTN; ++kt) {
        bf16x8 a = *((const bf16x8*)&Afrag[(size_t)(kt * 64 + l) * 8]);
        acc0 = __builtin_amdgcn_mfma_f32_16x16x32_bf16(a, B0[kt], acc0, 0, 0, 0);
        if (hasB1)
            acc1 = __builtin_amdgcn_mfma_f32_16x16x32_bf16(a, B1[kt], acc1, 0, 0, 0);
    }

    // ---- fused epilogue: bias + ReLU + layer-2 partials in-register ----
    float p[ONUM][4];
    #pragma unroll
    for (int o = 0; o < ONUM; ++o)
        #pragma unroll
        for (int r = 0; r < 4; ++r) p[o][r] = 0.f;

    #pragma unroll
    for (int r = 0; r < 4; ++r) {
        float h = acc0[r] + bb0; h = h > 0.f ? h : 0.f;
        p[0][r] = fmaf(h, w20, p[0][r]);
        p[1][r] = fmaf(h, w21, p[1][r]);
        p[2][r] = fmaf(h, w22, p[2][r]);
    }
    if (hasB1) {
        #pragma unroll
        for (int r = 0; r < 4; ++r) {
            float h = acc1[r] + bb1; h = h > 0.f ? h : 0.f;
            p[0][r] = fmaf(h, w23, p[0][r]);
            p[1][r] = fmaf(h, w24, p[1][r]);
            p[2][r] = fmaf(h, w25, p[2][r]);
        }
    }

    #pragma unroll
    for (int d = 1; d < 16; d <<= 1) {
        #pragma unroll
        for (int o = 0; o < ONUM; ++o)
            #pragma unroll
            for (int r = 0; r < 4; ++r)
                p[o][r] += __shfl_xor(p[o][r], d, 64);
    }
    if ((l & 15) == 0) {
        #pragma unroll
        for (int r = 0; r < 4; ++r) {
            int s = ((l >> 4) << 2) + r;
            #pragma unroll
            for (int o = 0; o < ONUM; ++o) psum[w][s][o] = p[o][r];
        }
    }
    __syncthreads();

    if (t < MB * ONUM) {
        int s = t / ONUM, o = t % ONUM;
        float v = b2[o];
        #pragma unroll
        for (int w8 = 0; w8 < 8; ++w8) v += psum[w8][s][o];
        out[(size_t)(s0 + s) * ONUM + o] = v;
    }
}

extern "C" void kernel_launch(void* const* d_in, const int* in_sizes, int n_in,
                              void* d_out, int out_size, void* d_ws, size_t ws_size,
                              hipStream_t stream) {
    const float* buffer        = (const float*)d_in[0];
    const float* W1            = (const float*)d_in[1];
    const float* b1            = (const float*)d_in[2];
    const float* W2            = (const float*)d_in[3];
    const float* b2            = (const float*)d_in[4];
    const int*   buffer_index  = (const int*)d_in[5];
    const int*   stack_indexes = (const int*)d_in[6];
    const int*   stack_len     = (const int*)d_in[7];
    float*       out           = (float*)d_out;

    parser_fused<<<Bq / MB, NTHR, 0, stream>>>(
        buffer, W1, b1, W2, b2, buffer_index, stack_indexes, stack_len, out);
}